// Round 9
// baseline (146.503 us; speedup 1.0000x reference)
//
#include <hip/hip_runtime.h>
#include <math.h>

#define B_ 32
#define N_ 4096
#define D_ 1024
#define ROWS (B_ * N_)        // 131072 rows of x_full

#define P1_BLOCKS 2048
#define P1_THREADS 256
#define NWAVES (P1_BLOCKS * (P1_THREADS / 64))   // 8192 waves
#define ROWS_PER_WAVE (ROWS / NWAVES)            // 16
#define BLOCKS_PER_BATCH (P1_BLOCKS / B_)        // 64

// One counter per 256-byte stripe: 64 u32 apart. 2048 end-of-kernel atomics
// previously hammered 32 CONSECUTIVE u32 (1-2 cache lines); same-line
// atomics serialize at the coherence point (~50-65 us burst, R8's +57 us).
// Padding drops per-line contention 1024 -> 64.
#define CTR_STRIDE 64

typedef float f32x4 __attribute__((ext_vector_type(4)));

// ---------------------------------------------------------------------------
// Counters MUST start at 0 so old==63 identifies the TRUE last arrival.
// Tiny kernel (~2 us) instead of a fill node.
// ---------------------------------------------------------------------------
__global__ void init_counters(unsigned* __restrict__ counters) {
    if (threadIdx.x < B_) counters[threadIdx.x * CTR_STRIDE] = 0u;
}

// ---------------------------------------------------------------------------
// Fused kernel — R8's PROVEN fence-free protocol + padded counters.
//
// Phase 1 (all 2048 blocks): per row: logits = x·q/32 (masked), t = x·w.
//   One wave per 16 contiguous rows; float4 nontemporal coalesced loads;
//   q/w fragments in registers; row i's result parked in lane i.
//   Results stored with AGENT-scope atomic stores (global_store sc1:
//   write-through to the device coherence point — never dirty in local L2,
//   so no producer fence needed).
//
// Handoff: __syncthreads (vmcnt(0) drain -> sc1 stores at coherence point)
//   -> thread 0: relaxed AGENT fetch_add on this batch's padded counter.
//   old==63 = true last arrival. Finisher does ONE acquire __threadfence
//   (32 blocks total) and reads producers' results via sc1 loads.
//
// Phase 2 (last block per batch): softmax over the batch's 4096 logits;
//   writes alpha + score. Value-identical regardless of which block is last
//   -> deterministic output.
// ---------------------------------------------------------------------------
__global__ __launch_bounds__(256) void probe_fused(
    const float* __restrict__ x,            // [B*N, D]
    const float* __restrict__ q,            // [D]
    const float* __restrict__ w,            // [D]
    const unsigned char* __restrict__ mask_b,
    const unsigned* __restrict__ mask_i,
    float* __restrict__ logits,             // ws [B*N]
    float* __restrict__ tvals,              // ws [B*N]
    unsigned* __restrict__ counters,        // ws [B*CTR_STRIDE], zeroed
    const float* __restrict__ head_b,       // [1]
    float* __restrict__ out)                // [0..B): scores, [B..): alpha
{
    const int lane  = threadIdx.x & 63;
    const int gwave = (int)((blockIdx.x * blockDim.x + threadIdx.x) >> 6);
    const int base  = gwave * ROWS_PER_WAVE;

    // Inline mask-layout sniff (byte-bool vs int32): uniform, L2-hot words.
    // All-true byte mask reads as 0x01010101 (>1) -> byte mode.
    const bool use_i32 = (__ballot(mask_i[lane] <= 1u) == ~0ull);

    // Hoist this lane's q/w fragments (16 floats each) into registers.
    const f32x4* q4 = (const f32x4*)q;
    const f32x4* w4 = (const f32x4*)w;
    f32x4 qv[4], wv[4];
#pragma unroll
    for (int j = 0; j < 4; ++j) {
        qv[j] = q4[j * 64 + lane];
        wv[j] = w4[j * 64 + lane];
    }

    float lq = 0.f, lw = 0.f;   // lane i ends up holding row (base+i)'s results

#pragma unroll 4
    for (int i = 0; i < ROWS_PER_WAVE; ++i) {
        const f32x4* xr = (const f32x4*)(x + (size_t)(base + i) * D_);
        f32x4 xv[4];
#pragma unroll
        for (int j = 0; j < 4; ++j)
            xv[j] = __builtin_nontemporal_load(&xr[j * 64 + lane]);

        float aq = 0.f, aw = 0.f;
#pragma unroll
        for (int j = 0; j < 4; ++j) {
            aq += xv[j].x * qv[j].x + xv[j].y * qv[j].y
                + xv[j].z * qv[j].z + xv[j].w * qv[j].w;
            aw += xv[j].x * wv[j].x + xv[j].y * wv[j].y
                + xv[j].z * wv[j].z + xv[j].w * wv[j].w;
        }
#pragma unroll
        for (int off = 32; off; off >>= 1) {
            aq += __shfl_xor(aq, off);
            aw += __shfl_xor(aw, off);
        }
        if (lane == i) { lq = aq; lw = aw; }   // park row i's result in lane i
    }

    if (lane < ROWS_PER_WAVE) {
        const int row = base + lane;
        const bool m = use_i32 ? (mask_i[row] != 0u) : (mask_b[row] != 0);
        const float lg = m ? lq * 0.03125f : -INFINITY;  // 1/sqrt(1024)
        // sc1 write-through stores: reach the device coherence point.
        __hip_atomic_store(&logits[row], lg, __ATOMIC_RELAXED,
                           __HIP_MEMORY_SCOPE_AGENT);
        __hip_atomic_store(&tvals[row], lw, __ATOMIC_RELAXED,
                           __HIP_MEMORY_SCOPE_AGENT);
    }

    // ---------------- last-block-done handoff ----------------
    const int b = (int)(blockIdx.x >> 6);    // 64 blocks per batch
    __shared__ int s_fin;
    __syncthreads();   // vmcnt(0) drain: sc1 stores at coherence point
    if (threadIdx.x == 0) {
        unsigned old = __hip_atomic_fetch_add(&counters[b * CTR_STRIDE], 1u,
                                              __ATOMIC_RELAXED,
                                              __HIP_MEMORY_SCOPE_AGENT);
        s_fin = (old == BLOCKS_PER_BATCH - 1);   // TRUE last arrival
    }
    __syncthreads();
    if (!s_fin) return;
    __threadfence();   // acquire side only: 32 blocks total, cheap

    // ---------------- phase 2: softmax for batch b ----------------
    const int tid   = threadIdx.x;
    const int wlane = tid & 63;
    const int wid   = tid >> 6;

    __shared__ float redmax[4];
    __shared__ float redsum[8];

    float* lb = logits + (size_t)b * N_;
    float* tb = tvals  + (size_t)b * N_;

    float lv[4][4], tv[4][4];
#pragma unroll
    for (int k = 0; k < 4; ++k) {
        const int e = (k * 256 + tid) * 4;
#pragma unroll
        for (int j = 0; j < 4; ++j) {
            lv[k][j] = __hip_atomic_load(&lb[e + j], __ATOMIC_RELAXED,
                                         __HIP_MEMORY_SCOPE_AGENT);
            tv[k][j] = __hip_atomic_load(&tb[e + j], __ATOMIC_RELAXED,
                                         __HIP_MEMORY_SCOPE_AGENT);
        }
    }

    // block max
    float m = -INFINITY;
#pragma unroll
    for (int k = 0; k < 4; ++k)
#pragma unroll
        for (int j = 0; j < 4; ++j) m = fmaxf(m, lv[k][j]);
#pragma unroll
    for (int off = 32; off; off >>= 1) m = fmaxf(m, __shfl_xor(m, off));
    if (wlane == 0) redmax[wid] = m;
    __syncthreads();
    m = fmaxf(fmaxf(redmax[0], redmax[1]), fmaxf(redmax[2], redmax[3]));

    // exp + partial sums
    float se = 0.f, set = 0.f;
    float ev[4][4];
#pragma unroll
    for (int k = 0; k < 4; ++k)
#pragma unroll
        for (int j = 0; j < 4; ++j) {
            ev[k][j] = __expf(lv[k][j] - m);
            se  += ev[k][j];
            set += ev[k][j] * tv[k][j];
        }
#pragma unroll
    for (int off = 32; off; off >>= 1) {
        se  += __shfl_xor(se, off);
        set += __shfl_xor(set, off);
    }
    if (wlane == 0) { redsum[wid] = se; redsum[4 + wid] = set; }
    __syncthreads();
    se  = redsum[0] + redsum[1] + redsum[2] + redsum[3];
    set = redsum[4] + redsum[5] + redsum[6] + redsum[7];

    const float inv = 1.0f / se;

    // write alpha (offset by B scores at the front of d_out)
    float4* a4 = (float4*)(out + B_ + (size_t)b * N_);
#pragma unroll
    for (int k = 0; k < 4; ++k) {
        float4 a;
        a.x = ev[k][0] * inv; a.y = ev[k][1] * inv;
        a.z = ev[k][2] * inv; a.w = ev[k][3] * inv;
        a4[k * 256 + tid] = a;
    }

    if (tid == 0) out[b] = set * inv + head_b[0];
}

// ---------------------------------------------------------------------------
extern "C" void kernel_launch(void* const* d_in, const int* in_sizes, int n_in,
                              void* d_out, int out_size, void* d_ws, size_t ws_size,
                              hipStream_t stream) {
    // setup_inputs order: x_final, x_full, mask, q, head_w, head_b
    const float* x_full = (const float*)d_in[1];
    const void*  mask   = d_in[2];
    const float* q      = (const float*)d_in[3];
    const float* head_w = (const float*)d_in[4];
    const float* head_b = (const float*)d_in[5];
    float* out = (float*)d_out;

    // workspace: logits [ROWS] f32 | tvals [ROWS] f32 | counters (padded)
    float*    logits   = (float*)d_ws;
    float*    tvals    = logits + ROWS;
    unsigned* counters = (unsigned*)(tvals + ROWS);   // B_*CTR_STRIDE u32 = 8 KB

    init_counters<<<1, 64, 0, stream>>>(counters);

    probe_fused<<<P1_BLOCKS, P1_THREADS, 0, stream>>>(
        x_full, q, head_w,
        (const unsigned char*)mask, (const unsigned*)mask,
        logits, tvals, counters, head_b, out);
}

// Round 10
// 88.328 us; speedup vs baseline: 1.6586x; 1.6586x over previous
//
#include <hip/hip_runtime.h>
#include <math.h>

#define B_ 32
#define N_ 4096
#define D_ 1024
#define ROWS (B_ * N_)        // 131072 rows of x_full

#define P1_BLOCKS 2048
#define P1_THREADS 256
#define NWAVES (P1_BLOCKS * (P1_THREADS / 64))   // 8192 waves
#define ROWS_PER_WAVE (ROWS / NWAVES)            // 16

typedef float f32x4 __attribute__((ext_vector_type(4)));

// ---------------------------------------------------------------------------
// R2 configuration — best verified (88.6 us). Fused single-kernel variants
// (R3..R9) all cost +57..+150 us in handoff protocol overhead; the plain
// second dispatch is cheaper than any device-side consensus on this HW.
//
// Pass 1: per row (b,n): logits = x·q/32 (masked), t = x·w.
// One wave per 16 contiguous rows; float4 nontemporal coalesced loads;
// q/w fragments in registers; row i's result parked in lane i, then one
// coalesced 16-lane store. Kernel boundary provides device-wide visibility
// for pass 2 (no fences needed).
// ---------------------------------------------------------------------------
__global__ __launch_bounds__(256) void probe_pass1(
    const float* __restrict__ x,            // [B*N, D]
    const float* __restrict__ q,            // [D]
    const float* __restrict__ w,            // [D]
    const unsigned char* __restrict__ mask_b,
    const unsigned* __restrict__ mask_i,
    float* __restrict__ logits,             // [B*N]
    float* __restrict__ tvals)              // [B*N]
{
    const int lane  = threadIdx.x & 63;
    const int gwave = (int)((blockIdx.x * blockDim.x + threadIdx.x) >> 6);
    const int base  = gwave * ROWS_PER_WAVE;

    // Inline mask-layout sniff (byte-bool vs int32): uniform, L2-hot words.
    // All-true byte mask reads as 0x01010101 (>1) -> byte mode.
    const bool use_i32 = (__ballot(mask_i[lane] <= 1u) == ~0ull);

    // Hoist this lane's q/w fragments (16 floats each) into registers.
    const f32x4* q4 = (const f32x4*)q;
    const f32x4* w4 = (const f32x4*)w;
    f32x4 qv[4], wv[4];
#pragma unroll
    for (int j = 0; j < 4; ++j) {
        qv[j] = q4[j * 64 + lane];
        wv[j] = w4[j * 64 + lane];
    }

    float lq = 0.f, lw = 0.f;   // lane i ends up holding row (base+i)'s results

#pragma unroll 4
    for (int i = 0; i < ROWS_PER_WAVE; ++i) {
        const f32x4* xr = (const f32x4*)(x + (size_t)(base + i) * D_);
        f32x4 xv[4];
#pragma unroll
        for (int j = 0; j < 4; ++j)
            xv[j] = __builtin_nontemporal_load(&xr[j * 64 + lane]);

        float aq = 0.f, aw = 0.f;
#pragma unroll
        for (int j = 0; j < 4; ++j) {
            aq += xv[j].x * qv[j].x + xv[j].y * qv[j].y
                + xv[j].z * qv[j].z + xv[j].w * qv[j].w;
            aw += xv[j].x * wv[j].x + xv[j].y * wv[j].y
                + xv[j].z * wv[j].z + xv[j].w * wv[j].w;
        }
#pragma unroll
        for (int off = 32; off; off >>= 1) {
            aq += __shfl_xor(aq, off);
            aw += __shfl_xor(aw, off);
        }
        if (lane == i) { lq = aq; lw = aw; }   // park row i's result in lane i
    }

    if (lane < ROWS_PER_WAVE) {
        const int row = base + lane;
        const bool m = use_i32 ? (mask_i[row] != 0u) : (mask_b[row] != 0);
        logits[row] = m ? lq * 0.03125f : -INFINITY;   // 1/sqrt(1024) = 1/32
        tvals[row]  = lw;
    }
}

// ---------------------------------------------------------------------------
// Pass 2: per batch b, softmax over N=4096 logits; write alpha and
// scores[b] = (sum e*t)/(sum e) + head_b.  32 blocks x 256 threads.
// ---------------------------------------------------------------------------
__global__ __launch_bounds__(256) void probe_pass2(
    const float* __restrict__ logits,       // [B, N]
    const float* __restrict__ tvals,        // [B, N]
    const float* __restrict__ head_b,       // [1]
    float* __restrict__ out)                // [0..B): scores, [B..): alpha
{
    const int b    = blockIdx.x;
    const int tid  = threadIdx.x;
    const int lane = tid & 63;
    const int wid  = tid >> 6;

    __shared__ float redmax[4];
    __shared__ float redsum[8];

    const float4* l4 = (const float4*)(logits + (size_t)b * N_);
    const float4* t4 = (const float4*)(tvals  + (size_t)b * N_);

    float4 lv[4], tv[4];
#pragma unroll
    for (int k = 0; k < 4; ++k) {
        lv[k] = l4[k * 256 + tid];
        tv[k] = t4[k * 256 + tid];
    }

    // ---- block max ----
    float m = -INFINITY;
#pragma unroll
    for (int k = 0; k < 4; ++k)
        m = fmaxf(m, fmaxf(fmaxf(lv[k].x, lv[k].y), fmaxf(lv[k].z, lv[k].w)));
#pragma unroll
    for (int off = 32; off; off >>= 1) m = fmaxf(m, __shfl_xor(m, off));
    if (lane == 0) redmax[wid] = m;
    __syncthreads();
    m = fmaxf(fmaxf(redmax[0], redmax[1]), fmaxf(redmax[2], redmax[3]));

    // ---- exp + partial sums ----
    float se = 0.f, set = 0.f;
    float4 ev[4];
#pragma unroll
    for (int k = 0; k < 4; ++k) {
        ev[k].x = __expf(lv[k].x - m);
        ev[k].y = __expf(lv[k].y - m);
        ev[k].z = __expf(lv[k].z - m);
        ev[k].w = __expf(lv[k].w - m);
        se  += ev[k].x + ev[k].y + ev[k].z + ev[k].w;
        set += ev[k].x * tv[k].x + ev[k].y * tv[k].y
             + ev[k].z * tv[k].z + ev[k].w * tv[k].w;
    }
#pragma unroll
    for (int off = 32; off; off >>= 1) {
        se  += __shfl_xor(se, off);
        set += __shfl_xor(set, off);
    }
    if (lane == 0) { redsum[wid] = se; redsum[4 + wid] = set; }
    __syncthreads();
    se  = redsum[0] + redsum[1] + redsum[2] + redsum[3];
    set = redsum[4] + redsum[5] + redsum[6] + redsum[7];

    const float inv = 1.0f / se;

    // ---- write alpha (offset by B scores at the front of d_out) ----
    float4* a4 = (float4*)(out + B_ + (size_t)b * N_);
#pragma unroll
    for (int k = 0; k < 4; ++k) {
        float4 a;
        a.x = ev[k].x * inv; a.y = ev[k].y * inv;
        a.z = ev[k].z * inv; a.w = ev[k].w * inv;
        a4[k * 256 + tid] = a;
    }

    if (tid == 0) out[b] = set * inv + head_b[0];
}

// ---------------------------------------------------------------------------
extern "C" void kernel_launch(void* const* d_in, const int* in_sizes, int n_in,
                              void* d_out, int out_size, void* d_ws, size_t ws_size,
                              hipStream_t stream) {
    // setup_inputs order: x_final, x_full, mask, q, head_w, head_b
    const float* x_full = (const float*)d_in[1];
    const void*  mask   = d_in[2];
    const float* q      = (const float*)d_in[3];
    const float* head_w = (const float*)d_in[4];
    const float* head_b = (const float*)d_in[5];
    float* out = (float*)d_out;

    // workspace layout: logits [ROWS] f32 | tvals [ROWS] f32
    float* logits = (float*)d_ws;
    float* tvals  = logits + ROWS;

    probe_pass1<<<P1_BLOCKS, P1_THREADS, 0, stream>>>(
        x_full, q, head_w,
        (const unsigned char*)mask, (const unsigned*)mask,
        logits, tvals);

    probe_pass2<<<B_, 256, 0, stream>>>(logits, tvals, head_b, out);
}